// Round 1
// baseline (1203.004 us; speedup 1.0000x reference)
//
#include <hip/hip_runtime.h>
#include <hip/hip_bf16.h>
#include <math.h>

#define B_  4
#define T_  2048
#define D_  1024
#define H_  16
#define HD_ 64
#define U_  38
#define M_  (B_*T_)   // 8192

// ---------------------------------------------------------------------------
// Fused QKV projection. Grid (M/64, 48): blockIdx.y 0..15 -> q heads (norm
// only), 16..31 -> k n-tiles, 32..47 -> v n-tiles. 64x64 tile, 256 threads,
// 4x4 acc per thread. q is never stored: its epilogue computes the L1 norm
// per (b,h,t) deterministically via 16-lane shuffle reduce.
// ---------------------------------------------------------------------------
__global__ __launch_bounds__(256) void qkv_kernel(
    const float* __restrict__ x,
    const float* __restrict__ Wq, const float* __restrict__ bq,
    const float* __restrict__ Wk, const float* __restrict__ bk,
    const float* __restrict__ Wv, const float* __restrict__ bv,
    float* __restrict__ kout, float* __restrict__ vout,
    float* __restrict__ qnorm)
{
    __shared__ float xst[64][68];   // transposed: xst[k][row]
    __shared__ float wsh[64][68];   // wsh[k][col]
    const int m0 = blockIdx.x * 64;
    const int by = blockIdx.y;
    const int which = by >> 4;          // 0=q,1=k,2=v
    const int hn = by & 15;
    const int n0 = hn * 64;
    const float* W  = which==0 ? Wq : (which==1 ? Wk : Wv);
    const float* bb = which==0 ? bq : (which==1 ? bk : bv);
    const int tid = threadIdx.x;
    const int tx = tid & 15, ty = tid >> 4;

    float acc[4][4] = {};

    for (int k0 = 0; k0 < D_; k0 += 64) {
        #pragma unroll
        for (int rep = 0; rep < 4; ++rep) {
            int e = tid + rep*256;          // 0..1023
            int r = e >> 4, c4 = e & 15;
            float4 xv = *(const float4*)(x + (size_t)(m0 + r)*D_ + k0 + c4*4);
            xst[c4*4+0][r] = xv.x; xst[c4*4+1][r] = xv.y;
            xst[c4*4+2][r] = xv.z; xst[c4*4+3][r] = xv.w;
            float4 wv = *(const float4*)(W + (size_t)(k0 + r)*D_ + n0 + c4*4);
            *(float4*)&wsh[r][c4*4] = wv;
        }
        __syncthreads();
        #pragma unroll 8
        for (int kk = 0; kk < 64; ++kk) {
            float4 xa  = *(float4*)&xst[kk][ty*4];
            float4 wv4 = *(float4*)&wsh[kk][tx*4];
            acc[0][0] += xa.x*wv4.x; acc[0][1] += xa.x*wv4.y; acc[0][2] += xa.x*wv4.z; acc[0][3] += xa.x*wv4.w;
            acc[1][0] += xa.y*wv4.x; acc[1][1] += xa.y*wv4.y; acc[1][2] += xa.y*wv4.z; acc[1][3] += xa.y*wv4.w;
            acc[2][0] += xa.z*wv4.x; acc[2][1] += xa.z*wv4.y; acc[2][2] += xa.z*wv4.z; acc[2][3] += xa.z*wv4.w;
            acc[3][0] += xa.w*wv4.x; acc[3][1] += xa.w*wv4.y; acc[3][2] += xa.w*wv4.z; acc[3][3] += xa.w*wv4.w;
        }
        __syncthreads();
    }

    float4 bvec = *(const float4*)(bb + n0 + tx*4);
    if (which == 0) {
        // q-norm epilogue: per row, sum |q| over the 64 head dims.
        #pragma unroll
        for (int i = 0; i < 4; ++i) {
            float p = fabsf(acc[i][0]+bvec.x) + fabsf(acc[i][1]+bvec.y)
                    + fabsf(acc[i][2]+bvec.z) + fabsf(acc[i][3]+bvec.w);
            p += __shfl_xor(p, 8, 16);
            p += __shfl_xor(p, 4, 16);
            p += __shfl_xor(p, 2, 16);
            p += __shfl_xor(p, 1, 16);
            if (tx == 0) {
                int m = m0 + ty*4 + i;
                int b = m >> 11, t = m & (T_-1);
                qnorm[((size_t)b*H_ + hn)*T_ + t] = p;
            }
        }
    } else {
        float* outp = (which==1) ? kout : vout;
        #pragma unroll
        for (int i = 0; i < 4; ++i) {
            int m = m0 + ty*4 + i;
            float4 o;
            o.x = acc[i][0]+bvec.x; o.y = acc[i][1]+bvec.y;
            o.z = acc[i][2]+bvec.z; o.w = acc[i][3]+bvec.w;
            *(float4*)(outp + (size_t)m*D_ + n0 + tx*4) = o;
        }
    }
}

// ---------------------------------------------------------------------------
// Top-38 per (b,h): iterative argmax with lower-index tie-break (matches
// jax.lax.top_k). 64 blocks, deterministic.
// ---------------------------------------------------------------------------
__global__ __launch_bounds__(256) void topk_kernel(
    const float* __restrict__ qnorm, int* __restrict__ idxout)
{
    __shared__ float sv[T_];
    __shared__ float rv[256];
    __shared__ int   ri[256];
    const int blk = blockIdx.x;  // b*H + h
    const int tid = threadIdx.x;
    for (int i = tid; i < T_; i += 256) sv[i] = qnorm[(size_t)blk*T_ + i];
    __syncthreads();
    for (int it = 0; it < U_; ++it) {
        float bv_ = -3e38f; int bi_ = T_;
        for (int i = tid; i < T_; i += 256) {
            float v = sv[i];
            if (v > bv_) { bv_ = v; bi_ = i; }  // ascending scan => lower idx kept on ties
        }
        rv[tid] = bv_; ri[tid] = bi_;
        __syncthreads();
        for (int s = 128; s > 0; s >>= 1) {
            if (tid < s) {
                float ov = rv[tid+s]; int oi = ri[tid+s];
                if (ov > rv[tid] || (ov == rv[tid] && oi < ri[tid])) { rv[tid] = ov; ri[tid] = oi; }
            }
            __syncthreads();
        }
        if (tid == 0) { idxout[blk*U_ + it] = ri[0]; sv[ri[0]] = -3e38f; }
        __syncthreads();
    }
}

// ---------------------------------------------------------------------------
// Per selected row: recompute q row (38 rows/head only), QK^T over j<=t,
// softmax, PV. One block per (b,h,ui). 2432 blocks.
// ---------------------------------------------------------------------------
__global__ __launch_bounds__(256) void attn_kernel(
    const float* __restrict__ x, const float* __restrict__ Wq, const float* __restrict__ bq,
    const float* __restrict__ kbuf, const float* __restrict__ vbuf,
    const int* __restrict__ idxb, float* __restrict__ selo)
{
    __shared__ float qrow[64];
    __shared__ float sc[T_];
    __shared__ float red[256];
    const int blk = blockIdx.x;
    const int h  = (blk / U_) % H_;
    const int b  = blk / (U_*H_);
    const int t  = idxb[blk];
    const int L  = t + 1;
    const int tid = threadIdx.x;
    const int d = tid & 63, ch = tid >> 6;

    // recompute q row for this token (fp32)
    const float* xrow = x + ((size_t)b*T_ + t)*D_;
    float p = 0.f;
    for (int k = ch*256; k < ch*256 + 256; ++k)
        p += xrow[k] * Wq[(size_t)k*D_ + h*HD_ + d];
    red[tid] = p;
    __syncthreads();
    if (ch == 0) qrow[d] = red[d] + red[d+64] + red[d+128] + red[d+192] + bq[h*HD_+d];
    __syncthreads();

    // scores (causal: j <= t)
    float lmax = -3e38f;
    for (int j = tid; j < L; j += 256) {
        const float* kr = kbuf + ((size_t)b*T_ + j)*D_ + h*HD_;
        float s = 0.f;
        #pragma unroll
        for (int dd = 0; dd < 64; dd += 4) {
            float4 kv = *(const float4*)(kr + dd);
            s += qrow[dd]*kv.x + qrow[dd+1]*kv.y + qrow[dd+2]*kv.z + qrow[dd+3]*kv.w;
        }
        s *= 0.125f;
        sc[j] = s;
        lmax = fmaxf(lmax, s);
    }
    red[tid] = lmax; __syncthreads();
    for (int s2 = 128; s2 > 0; s2 >>= 1) { if (tid < s2) red[tid] = fmaxf(red[tid], red[tid+s2]); __syncthreads(); }
    float mx = red[0];
    __syncthreads();
    float lsum = 0.f;
    for (int j = tid; j < L; j += 256) { float e = __expf(sc[j] - mx); sc[j] = e; lsum += e; }
    red[tid] = lsum; __syncthreads();
    for (int s2 = 128; s2 > 0; s2 >>= 1) { if (tid < s2) red[tid] += red[tid+s2]; __syncthreads(); }
    float inv = 1.f / red[0];
    __syncthreads();

    // PV
    float a = 0.f;
    for (int j = ch; j < L; j += 4)
        a += sc[j] * vbuf[((size_t)b*T_ + j)*D_ + h*HD_ + d];
    red[tid] = a; __syncthreads();
    if (ch == 0)
        selo[(size_t)blk*HD_ + d] = (red[d] + red[d+64] + red[d+128] + red[d+192]) * inv;
}

// ---------------------------------------------------------------------------
// out = bo everywhere (non-selected rows contribute zeros through Wo)
// ---------------------------------------------------------------------------
__global__ __launch_bounds__(256) void fill_kernel(
    const float* __restrict__ bo, float* __restrict__ out)
{
    const size_t i = (size_t)blockIdx.x*256 + threadIdx.x;   // float4 index
    float4 bv = *(const float4*)(bo + ((i & 255) << 2));
    *(float4*)(out + i*4) = bv;
}

// ---------------------------------------------------------------------------
// Scatter: out[b, t, :] += sel_out[b,h,ui,:] @ Wo[h*64:(h+1)*64, :]
// One block per (b,h,ui); atomicAdd since heads may share rows.
// ---------------------------------------------------------------------------
__global__ __launch_bounds__(256) void oproj_kernel(
    const float* __restrict__ selo, const int* __restrict__ idxb,
    const float* __restrict__ Wo, float* __restrict__ out)
{
    __shared__ float sel[64];
    const int blk = blockIdx.x;
    const int h = (blk / U_) % H_;
    const int b = blk / (U_*H_);
    const int t = idxb[blk];
    const int tid = threadIdx.x;
    if (tid < 64) sel[tid] = selo[(size_t)blk*HD_ + tid];
    __syncthreads();
    float* orow = out + ((size_t)b*T_ + t)*D_;
    #pragma unroll
    for (int rep = 0; rep < 4; ++rep) {
        int n = tid + rep*256;
        float c = 0.f;
        #pragma unroll 8
        for (int dd = 0; dd < 64; ++dd)
            c += sel[dd] * Wo[(size_t)(h*HD_+dd)*D_ + n];
        atomicAdd(orow + n, c);
    }
}

// ---------------------------------------------------------------------------
extern "C" void kernel_launch(void* const* d_in, const int* in_sizes, int n_in,
                              void* d_out, int out_size, void* d_ws, size_t ws_size,
                              hipStream_t stream)
{
    const float* x  = (const float*)d_in[0];
    const float* Wq = (const float*)d_in[1];
    const float* bq = (const float*)d_in[2];
    const float* Wk = (const float*)d_in[3];
    const float* bk = (const float*)d_in[4];
    const float* Wv = (const float*)d_in[5];
    const float* bv = (const float*)d_in[6];
    const float* Wo = (const float*)d_in[7];
    const float* bo = (const float*)d_in[8];
    float* out = (float*)d_out;

    char* ws = (char*)d_ws;
    float* kbuf  = (float*)(ws);                       // 33,554,432 B
    float* vbuf  = (float*)(ws + 33554432);            // 33,554,432 B
    float* qnorm = (float*)(ws + 67108864);            //    524,288 B
    int*   idxb  = (int*)  (ws + 67633152);            //     16,384 B (padded)
    float* selo  = (float*)(ws + 67649536);            //    622,592 B

    dim3 g1(M_/64, 48);
    qkv_kernel<<<g1, 256, 0, stream>>>(x, Wq, bq, Wk, bk, Wv, bv, kbuf, vbuf, qnorm);
    topk_kernel<<<B_*H_, 256, 0, stream>>>(qnorm, idxb);
    attn_kernel<<<B_*H_*U_, 256, 0, stream>>>(x, Wq, bq, kbuf, vbuf, idxb, selo);
    fill_kernel<<<(M_*D_/4)/256, 256, 0, stream>>>(bo, out);
    oproj_kernel<<<B_*H_*U_, 256, 0, stream>>>(selo, idxb, Wo, out);
}

// Round 2
// 577.351 us; speedup vs baseline: 2.0837x; 2.0837x over previous
//
#include <hip/hip_runtime.h>
#include <hip/hip_bf16.h>
#include <math.h>

#define B_  4
#define T_  2048
#define D_  1024
#define H_  16
#define HD_ 64
#define U_  38
#define M_  (B_*T_)   // 8192

typedef __attribute__((ext_vector_type(8))) short bf16x8;
typedef __attribute__((ext_vector_type(4))) float f32x4;

__device__ __forceinline__ short f2b(float f) {
    __hip_bfloat16 b = __float2bfloat16(f);
    return *(short*)&b;
}
__device__ __forceinline__ float b2f(short s) {
    __hip_bfloat16 b = *(__hip_bfloat16*)&s;
    return __bfloat162float(b);
}

__device__ __forceinline__ void gload16(const void* g, void* l) {
    __builtin_amdgcn_global_load_lds(
        (const __attribute__((address_space(1))) unsigned int*)g,
        (__attribute__((address_space(3))) unsigned int*)l,
        16, 0, 0);
}

// ---------------------------------------------------------------------------
// x [8192][1024] fp32 -> xh, xl bf16 (hi + residual-lo split)
// ---------------------------------------------------------------------------
__global__ __launch_bounds__(256) void convx_kernel(
    const float* __restrict__ x, short* __restrict__ xh, short* __restrict__ xl)
{
    const size_t i = ((size_t)blockIdx.x * 256 + threadIdx.x) * 4;
    float4 v = *(const float4*)(x + i);
    short4 h, l;
    h.x = f2b(v.x); l.x = f2b(v.x - b2f(h.x));
    h.y = f2b(v.y); l.y = f2b(v.y - b2f(h.y));
    h.z = f2b(v.z); l.z = f2b(v.z - b2f(h.z));
    h.w = f2b(v.w); l.w = f2b(v.w - b2f(h.w));
    *(short4*)(xh + i) = h;
    *(short4*)(xl + i) = l;
}

// ---------------------------------------------------------------------------
// Transpose weights to [n][k] bf16. z=0: Wq -> wqh+wql (split). z=1: Wk ->
// wkvt rows 0..1023. z=2: Wv -> wkvt rows 1024..2047.
// ---------------------------------------------------------------------------
__global__ __launch_bounds__(256) void convw_kernel(
    const float* __restrict__ Wq, const float* __restrict__ Wk, const float* __restrict__ Wv,
    short* __restrict__ wqh, short* __restrict__ wql, short* __restrict__ wkvt)
{
    __shared__ float tile[32][33];
    const int which = blockIdx.z;
    const float* W = which == 0 ? Wq : (which == 1 ? Wk : Wv);
    const int k0 = blockIdx.y * 32, n0 = blockIdx.x * 32;
    const int tx = threadIdx.x & 31, ty = threadIdx.x >> 5;
    #pragma unroll
    for (int r = ty; r < 32; r += 8)
        tile[r][tx] = W[(size_t)(k0 + r) * D_ + n0 + tx];
    __syncthreads();
    #pragma unroll
    for (int r = ty; r < 32; r += 8) {
        float v = tile[tx][r];                 // W[k0+tx][n0+r]
        size_t o = (size_t)(n0 + r) * D_ + k0 + tx;
        if (which == 0) {
            short h = f2b(v);
            wqh[o] = h;
            wql[o] = f2b(v - b2f(h));
        } else {
            wkvt[(size_t)(which - 1) * D_ * D_ + o] = f2b(v);
        }
    }
}

// ---------------------------------------------------------------------------
// K/V projection: C[8192][2048] = xh @ wkvt^T (bf16 MFMA), +bias, store bf16.
// 128x128 tile, BK=32, 4 waves, 16x16x32 MFMA, global_load_lds staging.
// ---------------------------------------------------------------------------
__global__ __launch_bounds__(256) void kv_gemm(
    const short* __restrict__ xh, const short* __restrict__ wkvt,
    const float* __restrict__ bk, const float* __restrict__ bv,
    short* __restrict__ kb, short* __restrict__ vb)
{
    __shared__ short As[128 * 32];
    __shared__ short Bs[128 * 32];
    const int tid = threadIdx.x, wid = tid >> 6, lane = tid & 63;
    const int m0 = blockIdx.x * 128;
    const int n0 = blockIdx.y * 128;
    const int wr = (wid >> 1) * 64, wc = (wid & 1) * 64;

    f32x4 acc[4][4];
    #pragma unroll
    for (int i = 0; i < 4; ++i)
        #pragma unroll
        for (int j = 0; j < 4; ++j)
            acc[i][j] = (f32x4){0.f, 0.f, 0.f, 0.f};

    const int srow = lane >> 2, scol = (lane & 3) * 8;

    for (int k0 = 0; k0 < D_; k0 += 32) {
        #pragma unroll
        for (int cc = 0; cc < 2; ++cc) {
            int c = wid + cc * 4;
            int r = c * 16 + srow;
            gload16(xh   + (size_t)(m0 + r) * D_ + k0 + scol, (char*)As + c * 1024);
            gload16(wkvt + (size_t)(n0 + r) * D_ + k0 + scol, (char*)Bs + c * 1024);
        }
        asm volatile("s_waitcnt vmcnt(0)" ::: "memory");
        __syncthreads();
        bf16x8 a[4], b[4];
        #pragma unroll
        for (int i = 0; i < 4; ++i)
            a[i] = *(bf16x8*)&As[(wr + i * 16 + (lane & 15)) * 32 + (lane >> 4) * 8];
        #pragma unroll
        for (int j = 0; j < 4; ++j)
            b[j] = *(bf16x8*)&Bs[(wc + j * 16 + (lane & 15)) * 32 + (lane >> 4) * 8];
        #pragma unroll
        for (int i = 0; i < 4; ++i)
            #pragma unroll
            for (int j = 0; j < 4; ++j)
                acc[i][j] = __builtin_amdgcn_mfma_f32_16x16x32_bf16(a[i], b[j], acc[i][j], 0, 0, 0);
        __syncthreads();
    }

    // epilogue: C/D layout col=lane&15, row=(lane>>4)*4+reg
    #pragma unroll
    for (int i = 0; i < 4; ++i)
        #pragma unroll
        for (int j = 0; j < 4; ++j)
            #pragma unroll
            for (int r = 0; r < 4; ++r) {
                int row = m0 + wr + i * 16 + (lane >> 4) * 4 + r;
                int col = n0 + wc + j * 16 + (lane & 15);
                float bias = (col < D_) ? bk[col] : bv[col - D_];
                float val = acc[i][j][r] + bias;
                if (col < D_) kb[(size_t)row * D_ + col] = f2b(val);
                else          vb[(size_t)row * D_ + col - D_] = f2b(val);
            }
}

// ---------------------------------------------------------------------------
// Q-norm: 4-product split-bf16 GEMM (xh+xl)@(wqh+wql)^T, fp32 acc; epilogue
// computes per-(b,h,t) L1 norm (never stores q). Wave covers exactly 1 head.
// ---------------------------------------------------------------------------
__global__ __launch_bounds__(256) void q_gemm(
    const short* __restrict__ xh, const short* __restrict__ xl,
    const short* __restrict__ wqh, const short* __restrict__ wql,
    const float* __restrict__ bq, float* __restrict__ qnorm)
{
    __shared__ short Ah[128 * 32], Al[128 * 32], Bh[128 * 32], Bl[128 * 32];
    const int tid = threadIdx.x, wid = tid >> 6, lane = tid & 63;
    const int m0 = blockIdx.x * 128;
    const int n0 = blockIdx.y * 128;
    const int wr = (wid >> 1) * 64, wc = (wid & 1) * 64;

    f32x4 acc[4][4];
    #pragma unroll
    for (int i = 0; i < 4; ++i)
        #pragma unroll
        for (int j = 0; j < 4; ++j)
            acc[i][j] = (f32x4){0.f, 0.f, 0.f, 0.f};

    const int srow = lane >> 2, scol = (lane & 3) * 8;

    for (int k0 = 0; k0 < D_; k0 += 32) {
        #pragma unroll
        for (int cc = 0; cc < 2; ++cc) {
            int c = wid + cc * 4;
            int r = c * 16 + srow;
            size_t ao = (size_t)(m0 + r) * D_ + k0 + scol;
            size_t bo = (size_t)(n0 + r) * D_ + k0 + scol;
            gload16(xh  + ao, (char*)Ah + c * 1024);
            gload16(xl  + ao, (char*)Al + c * 1024);
            gload16(wqh + bo, (char*)Bh + c * 1024);
            gload16(wql + bo, (char*)Bl + c * 1024);
        }
        asm volatile("s_waitcnt vmcnt(0)" ::: "memory");
        __syncthreads();
        bf16x8 ah[4], al[4], bh[4], bl[4];
        #pragma unroll
        for (int i = 0; i < 4; ++i) {
            int o = (wr + i * 16 + (lane & 15)) * 32 + (lane >> 4) * 8;
            ah[i] = *(bf16x8*)&Ah[o];
            al[i] = *(bf16x8*)&Al[o];
        }
        #pragma unroll
        for (int j = 0; j < 4; ++j) {
            int o = (wc + j * 16 + (lane & 15)) * 32 + (lane >> 4) * 8;
            bh[j] = *(bf16x8*)&Bh[o];
            bl[j] = *(bf16x8*)&Bl[o];
        }
        #pragma unroll
        for (int i = 0; i < 4; ++i)
            #pragma unroll
            for (int j = 0; j < 4; ++j) {
                acc[i][j] = __builtin_amdgcn_mfma_f32_16x16x32_bf16(ah[i], bh[j], acc[i][j], 0, 0, 0);
                acc[i][j] = __builtin_amdgcn_mfma_f32_16x16x32_bf16(ah[i], bl[j], acc[i][j], 0, 0, 0);
                acc[i][j] = __builtin_amdgcn_mfma_f32_16x16x32_bf16(al[i], bh[j], acc[i][j], 0, 0, 0);
                acc[i][j] = __builtin_amdgcn_mfma_f32_16x16x32_bf16(al[i], bl[j], acc[i][j], 0, 0, 0);
            }
        __syncthreads();
    }

    // epilogue: wave's 64 cols == one head -> per-row |q| sum across 4 frag
    // cols + 16-lane shuffle reduce.
    const int h = (n0 + wc) >> 6;
    #pragma unroll
    for (int i = 0; i < 4; ++i)
        #pragma unroll
        for (int r = 0; r < 4; ++r) {
            float s = 0.f;
            #pragma unroll
            for (int j = 0; j < 4; ++j) {
                int col = n0 + wc + j * 16 + (lane & 15);
                s += fabsf(acc[i][j][r] + bq[col]);
            }
            s += __shfl_xor(s, 1);
            s += __shfl_xor(s, 2);
            s += __shfl_xor(s, 4);
            s += __shfl_xor(s, 8);
            if ((lane & 15) == 0) {
                int row = m0 + wr + i * 16 + (lane >> 4) * 4 + r;
                int b = row >> 11, t = row & (T_ - 1);
                qnorm[((size_t)b * H_ + h) * T_ + t] = s;
            }
        }
}

// ---------------------------------------------------------------------------
// Top-38 per (b,h): iterative argmax, lower-index tie-break. Deterministic.
// ---------------------------------------------------------------------------
__global__ __launch_bounds__(256) void topk_kernel(
    const float* __restrict__ qnorm, int* __restrict__ idxout)
{
    __shared__ float sv[T_];
    __shared__ float rv[256];
    __shared__ int   ri[256];
    const int blk = blockIdx.x;
    const int tid = threadIdx.x;
    for (int i = tid; i < T_; i += 256) sv[i] = qnorm[(size_t)blk * T_ + i];
    __syncthreads();
    for (int it = 0; it < U_; ++it) {
        float bv_ = -3e38f; int bi_ = T_;
        for (int i = tid; i < T_; i += 256) {
            float v = sv[i];
            if (v > bv_) { bv_ = v; bi_ = i; }
        }
        rv[tid] = bv_; ri[tid] = bi_;
        __syncthreads();
        for (int s = 128; s > 0; s >>= 1) {
            if (tid < s) {
                float ov = rv[tid + s]; int oi = ri[tid + s];
                if (ov > rv[tid] || (ov == rv[tid] && oi < ri[tid])) { rv[tid] = ov; ri[tid] = oi; }
            }
            __syncthreads();
        }
        if (tid == 0) { idxout[blk * U_ + it] = ri[0]; sv[ri[0]] = -3e38f; }
        __syncthreads();
    }
}

// ---------------------------------------------------------------------------
// Per selected row: recompute q (fp32 x · split-bf16 Wq^T rows, contiguous),
// scores vs bf16 K, softmax, PV vs bf16 V. One block per (b,h,ui).
// ---------------------------------------------------------------------------
__global__ __launch_bounds__(256) void attn_kernel(
    const float* __restrict__ x,
    const short* __restrict__ wqh, const short* __restrict__ wql,
    const float* __restrict__ bq,
    const short* __restrict__ kb, const short* __restrict__ vb,
    const int* __restrict__ idxb, float* __restrict__ selo)
{
    __shared__ float qrow[64];
    __shared__ float sc[T_];
    __shared__ float red[256];
    const int blk = blockIdx.x;
    const int h  = (blk / U_) % H_;
    const int b  = blk / (U_ * H_);
    const int t  = idxb[blk];
    const int L  = t + 1;
    const int tid = threadIdx.x;
    const int d = tid & 63, ch = tid >> 6;

    // q row: dot(x[b,t,:], Wq^T[h*64+d,:]) with hi+lo reconstruction
    const float* xrow = x + ((size_t)b * T_ + t) * D_;
    const short* wh = wqh + (size_t)(h * HD_ + d) * D_;
    const short* wl = wql + (size_t)(h * HD_ + d) * D_;
    float p = 0.f;
    for (int k = ch * 256; k < ch * 256 + 256; ++k)
        p += xrow[k] * (b2f(wh[k]) + b2f(wl[k]));
    red[tid] = p;
    __syncthreads();
    if (ch == 0) qrow[d] = red[d] + red[d + 64] + red[d + 128] + red[d + 192] + bq[h * HD_ + d];
    __syncthreads();

    // scores (causal: j <= t)
    float lmax = -3e38f;
    for (int j = tid; j < L; j += 256) {
        const short* kr = kb + ((size_t)b * T_ + j) * D_ + h * HD_;
        float s = 0.f;
        #pragma unroll
        for (int dd = 0; dd < 64; dd += 8) {
            bf16x8 kv8 = *(const bf16x8*)(kr + dd);
            s += qrow[dd + 0] * b2f(kv8[0]) + qrow[dd + 1] * b2f(kv8[1])
               + qrow[dd + 2] * b2f(kv8[2]) + qrow[dd + 3] * b2f(kv8[3])
               + qrow[dd + 4] * b2f(kv8[4]) + qrow[dd + 5] * b2f(kv8[5])
               + qrow[dd + 6] * b2f(kv8[6]) + qrow[dd + 7] * b2f(kv8[7]);
        }
        s *= 0.125f;
        sc[j] = s;
        lmax = fmaxf(lmax, s);
    }
    red[tid] = lmax; __syncthreads();
    for (int s2 = 128; s2 > 0; s2 >>= 1) { if (tid < s2) red[tid] = fmaxf(red[tid], red[tid + s2]); __syncthreads(); }
    float mx = red[0];
    __syncthreads();
    float lsum = 0.f;
    for (int j = tid; j < L; j += 256) { float e = __expf(sc[j] - mx); sc[j] = e; lsum += e; }
    red[tid] = lsum; __syncthreads();
    for (int s2 = 128; s2 > 0; s2 >>= 1) { if (tid < s2) red[tid] += red[tid + s2]; __syncthreads(); }
    float inv = 1.f / red[0];
    __syncthreads();

    // PV
    float a = 0.f;
    for (int j = ch; j < L; j += 4)
        a += sc[j] * b2f(vb[((size_t)b * T_ + j) * D_ + h * HD_ + d]);
    red[tid] = a; __syncthreads();
    if (ch == 0)
        selo[(size_t)blk * HD_ + d] = (red[d] + red[d + 64] + red[d + 128] + red[d + 192]) * inv;
}

// ---------------------------------------------------------------------------
__global__ __launch_bounds__(256) void fill_kernel(
    const float* __restrict__ bo, float* __restrict__ out)
{
    const size_t i = (size_t)blockIdx.x * 256 + threadIdx.x;   // float4 index
    float4 bv = *(const float4*)(bo + ((i & 255) << 2));
    *(float4*)(out + i * 4) = bv;
}

__global__ __launch_bounds__(256) void oproj_kernel(
    const float* __restrict__ selo, const int* __restrict__ idxb,
    const float* __restrict__ Wo, float* __restrict__ out)
{
    __shared__ float sel[64];
    const int blk = blockIdx.x;
    const int h = (blk / U_) % H_;
    const int b = blk / (U_ * H_);
    const int t = idxb[blk];
    const int tid = threadIdx.x;
    if (tid < 64) sel[tid] = selo[(size_t)blk * HD_ + tid];
    __syncthreads();
    float* orow = out + ((size_t)b * T_ + t) * D_;
    #pragma unroll
    for (int rep = 0; rep < 4; ++rep) {
        int n = tid + rep * 256;
        float c = 0.f;
        #pragma unroll 8
        for (int dd = 0; dd < 64; ++dd)
            c += sel[dd] * Wo[(size_t)(h * HD_ + dd) * D_ + n];
        atomicAdd(orow + n, c);
    }
}

// ---------------------------------------------------------------------------
extern "C" void kernel_launch(void* const* d_in, const int* in_sizes, int n_in,
                              void* d_out, int out_size, void* d_ws, size_t ws_size,
                              hipStream_t stream)
{
    const float* x  = (const float*)d_in[0];
    const float* Wq = (const float*)d_in[1];
    const float* bq = (const float*)d_in[2];
    const float* Wk = (const float*)d_in[3];
    const float* bk = (const float*)d_in[4];
    const float* Wv = (const float*)d_in[5];
    const float* bv = (const float*)d_in[6];
    const float* Wo = (const float*)d_in[7];
    const float* bo = (const float*)d_in[8];
    float* out = (float*)d_out;

    char* ws = (char*)d_ws;
    short* xh    = (short*)(ws);                        // 16,777,216
    short* xl    = (short*)(ws + 16777216);             // 16,777,216
    short* wqh   = (short*)(ws + 33554432);             //  2,097,152
    short* wql   = (short*)(ws + 35651584);             //  2,097,152
    short* wkvt  = (short*)(ws + 37748736);             //  4,194,304
    short* kb    = (short*)(ws + 41943040);             // 16,777,216
    short* vb    = (short*)(ws + 58720256);             // 16,777,216
    float* qnorm = (float*)(ws + 75497472);             //    524,288
    int*   idxb  = (int*)  (ws + 76021760);             //     16,384
    float* selo  = (float*)(ws + 76038144);             //    622,592

    convx_kernel<<<M_ * D_ / 1024, 256, 0, stream>>>(x, xh, xl);
    convw_kernel<<<dim3(32, 32, 3), 256, 0, stream>>>(Wq, Wk, Wv, wqh, wql, wkvt);
    kv_gemm<<<dim3(M_ / 128, 16), 256, 0, stream>>>(xh, wkvt, bk, bv, kb, vb);
    q_gemm<<<dim3(M_ / 128, 8), 256, 0, stream>>>(xh, xl, wqh, wql, bq, qnorm);
    topk_kernel<<<B_ * H_, 256, 0, stream>>>(qnorm, idxb);
    attn_kernel<<<B_ * H_ * U_, 256, 0, stream>>>(x, wqh, wql, bq, kb, vb, idxb, selo);
    fill_kernel<<<(M_ * D_ / 4) / 256, 256, 0, stream>>>(bo, out);
    oproj_kernel<<<B_ * H_ * U_, 256, 0, stream>>>(selo, idxb, Wo, out);
}

// Round 3
// 282.481 us; speedup vs baseline: 4.2587x; 2.0439x over previous
//
#include <hip/hip_runtime.h>
#include <hip/hip_bf16.h>
#include <math.h>

#define B_  4
#define T_  2048
#define D_  1024
#define H_  16
#define HD_ 64
#define U_  38
#define M_  (B_*T_)   // 8192
#define NC_ 8         // j-chunks per head
#define JC_ 256       // chunk length

typedef __attribute__((ext_vector_type(8))) short bf16x8;
typedef __attribute__((ext_vector_type(4))) float f32x4;

__device__ __forceinline__ short f2b(float f) {
    __hip_bfloat16 b = __float2bfloat16(f);
    return *(short*)&b;
}
__device__ __forceinline__ float b2f(short s) {
    __hip_bfloat16 b = *(__hip_bfloat16*)&s;
    return __bfloat162float(b);
}

__device__ __forceinline__ void gload16(const void* g, void* l) {
    __builtin_amdgcn_global_load_lds(
        (const __attribute__((address_space(1))) unsigned int*)g,
        (__attribute__((address_space(3))) unsigned int*)l,
        16, 0, 0);
}

// ---------------------------------------------------------------------------
// x [8192][1024] fp32 -> xh, xl bf16 (hi + residual-lo split)
// ---------------------------------------------------------------------------
__global__ __launch_bounds__(256) void convx_kernel(
    const float* __restrict__ x, short* __restrict__ xh, short* __restrict__ xl)
{
    const size_t i = ((size_t)blockIdx.x * 256 + threadIdx.x) * 4;
    float4 v = *(const float4*)(x + i);
    short4 h, l;
    h.x = f2b(v.x); l.x = f2b(v.x - b2f(h.x));
    h.y = f2b(v.y); l.y = f2b(v.y - b2f(h.y));
    h.z = f2b(v.z); l.z = f2b(v.z - b2f(h.z));
    h.w = f2b(v.w); l.w = f2b(v.w - b2f(h.w));
    *(short4*)(xh + i) = h;
    *(short4*)(xl + i) = l;
}

// ---------------------------------------------------------------------------
// Transpose weights to [n][k] bf16. z=0: Wq -> wqh+wql. z=1: Wk. z=2: Wv.
// ---------------------------------------------------------------------------
__global__ __launch_bounds__(256) void convw_kernel(
    const float* __restrict__ Wq, const float* __restrict__ Wk, const float* __restrict__ Wv,
    short* __restrict__ wqh, short* __restrict__ wql, short* __restrict__ wkvt)
{
    __shared__ float tile[32][33];
    const int which = blockIdx.z;
    const float* W = which == 0 ? Wq : (which == 1 ? Wk : Wv);
    const int k0 = blockIdx.y * 32, n0 = blockIdx.x * 32;
    const int tx = threadIdx.x & 31, ty = threadIdx.x >> 5;
    #pragma unroll
    for (int r = ty; r < 32; r += 8)
        tile[r][tx] = W[(size_t)(k0 + r) * D_ + n0 + tx];
    __syncthreads();
    #pragma unroll
    for (int r = ty; r < 32; r += 8) {
        float v = tile[tx][r];                 // W[k0+tx][n0+r]
        size_t o = (size_t)(n0 + r) * D_ + k0 + tx;
        if (which == 0) {
            short h = f2b(v);
            wqh[o] = h;
            wql[o] = f2b(v - b2f(h));
        } else {
            wkvt[(size_t)(which - 1) * D_ * D_ + o] = f2b(v);
        }
    }
}

// ---------------------------------------------------------------------------
// K/V projection -> [b][h][t][d] bf16 layout for attention.
// ---------------------------------------------------------------------------
__global__ __launch_bounds__(256) void kv_gemm(
    const short* __restrict__ xh, const short* __restrict__ wkvt,
    const float* __restrict__ bk, const float* __restrict__ bv,
    short* __restrict__ kb, short* __restrict__ vb)
{
    __shared__ short As[128 * 32];
    __shared__ short Bs[128 * 32];
    const int tid = threadIdx.x, wid = tid >> 6, lane = tid & 63;
    const int m0 = blockIdx.x * 128;
    const int n0 = blockIdx.y * 128;
    const int wr = (wid >> 1) * 64, wc = (wid & 1) * 64;

    f32x4 acc[4][4];
    #pragma unroll
    for (int i = 0; i < 4; ++i)
        #pragma unroll
        for (int j = 0; j < 4; ++j)
            acc[i][j] = (f32x4){0.f, 0.f, 0.f, 0.f};

    const int srow = lane >> 2, scol = (lane & 3) * 8;

    for (int k0 = 0; k0 < D_; k0 += 32) {
        #pragma unroll
        for (int cc = 0; cc < 2; ++cc) {
            int c = wid + cc * 4;
            int r = c * 16 + srow;
            gload16(xh   + (size_t)(m0 + r) * D_ + k0 + scol, (char*)As + c * 1024);
            gload16(wkvt + (size_t)(n0 + r) * D_ + k0 + scol, (char*)Bs + c * 1024);
        }
        asm volatile("s_waitcnt vmcnt(0)" ::: "memory");
        __syncthreads();
        bf16x8 a[4], b[4];
        #pragma unroll
        for (int i = 0; i < 4; ++i)
            a[i] = *(bf16x8*)&As[(wr + i * 16 + (lane & 15)) * 32 + (lane >> 4) * 8];
        #pragma unroll
        for (int j = 0; j < 4; ++j)
            b[j] = *(bf16x8*)&Bs[(wc + j * 16 + (lane & 15)) * 32 + (lane >> 4) * 8];
        #pragma unroll
        for (int i = 0; i < 4; ++i)
            #pragma unroll
            for (int j = 0; j < 4; ++j)
                acc[i][j] = __builtin_amdgcn_mfma_f32_16x16x32_bf16(a[i], b[j], acc[i][j], 0, 0, 0);
        __syncthreads();
    }

    #pragma unroll
    for (int i = 0; i < 4; ++i)
        #pragma unroll
        for (int j = 0; j < 4; ++j)
            #pragma unroll
            for (int r = 0; r < 4; ++r) {
                int row = m0 + wr + i * 16 + (lane >> 4) * 4 + r;
                int col = n0 + wc + j * 16 + (lane & 15);
                int bb = row >> 11, t = row & (T_ - 1);
                float bias = (col < D_) ? bk[col] : bv[col - D_];
                float val = acc[i][j][r] + bias;
                int cc2 = col & (D_ - 1);
                int hh = cc2 >> 6, dd = cc2 & 63;
                short* dst = (col < D_) ? kb : vb;
                dst[(((size_t)bb * H_ + hh) * T_ + t) * HD_ + dd] = f2b(val);
            }
}

// ---------------------------------------------------------------------------
// Q: 3-product split-bf16 GEMM (xh·wh + xh·wl + xl·wh), fp32 acc. Writes
// per-(b,h,t) L1 norm (fp32-accurate, for ranking) and q values (bf16).
// ---------------------------------------------------------------------------
__global__ __launch_bounds__(256) void q_gemm(
    const short* __restrict__ xh, const short* __restrict__ xl,
    const short* __restrict__ wqh, const short* __restrict__ wql,
    const float* __restrict__ bq, float* __restrict__ qnorm,
    short* __restrict__ qbuf)
{
    __shared__ short Ah[128 * 32], Al[128 * 32], Bh[128 * 32], Bl[128 * 32];
    const int tid = threadIdx.x, wid = tid >> 6, lane = tid & 63;
    const int m0 = blockIdx.x * 128;
    const int n0 = blockIdx.y * 128;
    const int wr = (wid >> 1) * 64, wc = (wid & 1) * 64;

    f32x4 acc[4][4];
    #pragma unroll
    for (int i = 0; i < 4; ++i)
        #pragma unroll
        for (int j = 0; j < 4; ++j)
            acc[i][j] = (f32x4){0.f, 0.f, 0.f, 0.f};

    const int srow = lane >> 2, scol = (lane & 3) * 8;

    for (int k0 = 0; k0 < D_; k0 += 32) {
        #pragma unroll
        for (int cc = 0; cc < 2; ++cc) {
            int c = wid + cc * 4;
            int r = c * 16 + srow;
            size_t ao = (size_t)(m0 + r) * D_ + k0 + scol;
            size_t bo = (size_t)(n0 + r) * D_ + k0 + scol;
            gload16(xh  + ao, (char*)Ah + c * 1024);
            gload16(xl  + ao, (char*)Al + c * 1024);
            gload16(wqh + bo, (char*)Bh + c * 1024);
            gload16(wql + bo, (char*)Bl + c * 1024);
        }
        asm volatile("s_waitcnt vmcnt(0)" ::: "memory");
        __syncthreads();
        bf16x8 ah[4], al[4], bh[4], bl[4];
        #pragma unroll
        for (int i = 0; i < 4; ++i) {
            int o = (wr + i * 16 + (lane & 15)) * 32 + (lane >> 4) * 8;
            ah[i] = *(bf16x8*)&Ah[o];
            al[i] = *(bf16x8*)&Al[o];
        }
        #pragma unroll
        for (int j = 0; j < 4; ++j) {
            int o = (wc + j * 16 + (lane & 15)) * 32 + (lane >> 4) * 8;
            bh[j] = *(bf16x8*)&Bh[o];
            bl[j] = *(bf16x8*)&Bl[o];
        }
        #pragma unroll
        for (int i = 0; i < 4; ++i)
            #pragma unroll
            for (int j = 0; j < 4; ++j) {
                acc[i][j] = __builtin_amdgcn_mfma_f32_16x16x32_bf16(ah[i], bh[j], acc[i][j], 0, 0, 0);
                acc[i][j] = __builtin_amdgcn_mfma_f32_16x16x32_bf16(ah[i], bl[j], acc[i][j], 0, 0, 0);
                acc[i][j] = __builtin_amdgcn_mfma_f32_16x16x32_bf16(al[i], bh[j], acc[i][j], 0, 0, 0);
            }
        __syncthreads();
    }

    const int h = (n0 + wc) >> 6;
    #pragma unroll
    for (int i = 0; i < 4; ++i)
        #pragma unroll
        for (int r = 0; r < 4; ++r) {
            int row = m0 + wr + i * 16 + (lane >> 4) * 4 + r;
            float s = 0.f;
            #pragma unroll
            for (int j = 0; j < 4; ++j) {
                int col = n0 + wc + j * 16 + (lane & 15);
                float val = acc[i][j][r] + bq[col];
                qbuf[(size_t)row * D_ + col] = f2b(val);
                s += fabsf(val);
            }
            s += __shfl_xor(s, 1);
            s += __shfl_xor(s, 2);
            s += __shfl_xor(s, 4);
            s += __shfl_xor(s, 8);
            if ((lane & 15) == 0) {
                int b = row >> 11, t = row & (T_ - 1);
                qnorm[((size_t)b * H_ + h) * T_ + t] = s;
            }
        }
}

// ---------------------------------------------------------------------------
// Top-38 per (b,h): single wave, values register-resident, iterative argmax
// with lower-index tie-break. No syncthreads.
// ---------------------------------------------------------------------------
__global__ __launch_bounds__(64) void topk_kernel(
    const float* __restrict__ qnorm, int* __restrict__ idxout)
{
    const int g = blockIdx.x;
    const int lane = threadIdx.x;
    float v[32];
    const float* src = qnorm + (size_t)g * T_ + lane * 32;
    #pragma unroll
    for (int i = 0; i < 32; i += 4) {
        float4 t = *(const float4*)(src + i);
        v[i] = t.x; v[i + 1] = t.y; v[i + 2] = t.z; v[i + 3] = t.w;
    }
    unsigned removed = 0;
    float lm; int li;
    #pragma unroll
    for (int it = 0; it < U_ + 1; ++it) {
        // local argmax over non-removed (static indexing only)
        lm = -3e38f; li = 0;
        #pragma unroll
        for (int i = 0; i < 32; ++i) {
            bool ok = !((removed >> i) & 1u) && v[i] > lm;
            lm = ok ? v[i] : lm;
            li = ok ? i : li;
        }
        if (it == U_) break;
        float bm = lm; int bi = lane * 32 + li;
        #pragma unroll
        for (int off = 32; off; off >>= 1) {
            float om = __shfl_xor(bm, off);
            int   oi = __shfl_xor(bi, off);
            if (om > bm || (om == bm && oi < bi)) { bm = om; bi = oi; }
        }
        if (lane == 0) idxout[g * U_ + it] = bi;
        if ((bi >> 5) == lane) removed |= 1u << (bi & 31);
    }
}

// ---------------------------------------------------------------------------
// Attention partials: block = (g = b*16+h, chunk c). Reads K/V chunk once,
// computes scores for all 38 selected rows, per-chunk softmax stats, partial
// PV. bid = c*64+g keeps all chunks of a head on one XCD.
// ---------------------------------------------------------------------------
__global__ __launch_bounds__(256) void attn_part(
    const short* __restrict__ qbuf, const short* __restrict__ kb,
    const short* __restrict__ vb, const int* __restrict__ idxb,
    float* __restrict__ pm, float* __restrict__ pl, float* __restrict__ po)
{
    __shared__ float qs[U_][64];      // 9728 B
    __shared__ float p[U_][JC_];      // 38912 B
    __shared__ int   sidx[U_];
    const int bid = blockIdx.x;
    const int g = bid & 63;
    const int c = bid >> 6;
    const int b = g >> 4, h = g & 15;
    const int j0 = c * JC_;
    const int tid = threadIdx.x;
    const int wid = tid >> 6, lane = tid & 63;

    if (tid < U_) sidx[tid] = idxb[g * U_ + tid];
    __syncthreads();
    for (int e = tid; e < U_ * 64; e += 256) {
        int u = e >> 6, d = e & 63;
        qs[u][d] = b2f(qbuf[((size_t)b * T_ + sidx[u]) * D_ + h * HD_ + d]);
    }

    // K row for this thread's j (registers)
    const int tj = j0 + tid;
    float kf[64];
    const short* kr = kb + ((size_t)g * T_ + tj) * HD_;
    #pragma unroll
    for (int d8 = 0; d8 < 8; ++d8) {
        bf16x8 kv8 = *(const bf16x8*)(kr + d8 * 8);
        #pragma unroll
        for (int e = 0; e < 8; ++e) kf[d8 * 8 + e] = b2f(kv8[e]);
    }
    __syncthreads();

    // scores: p[u][tid]
    for (int u = 0; u < U_; ++u) {
        float s = -3e38f;
        if (tj <= sidx[u]) {
            s = 0.f;
            #pragma unroll
            for (int dd = 0; dd < 64; dd += 4) {
                float4 qv = *(float4*)&qs[u][dd];
                s += qv.x * kf[dd] + qv.y * kf[dd + 1] + qv.z * kf[dd + 2] + qv.w * kf[dd + 3];
            }
            s *= 0.125f;
        }
        p[u][tid] = s;
    }
    __syncthreads();

    // per-u chunk softmax stats; overwrite p with exp(s - m_c)
    for (int u = wid; u < U_; u += 4) {
        float v0 = p[u][lane], v1 = p[u][lane + 64], v2 = p[u][lane + 128], v3 = p[u][lane + 192];
        float m = fmaxf(fmaxf(v0, v1), fmaxf(v2, v3));
        #pragma unroll
        for (int off = 32; off; off >>= 1) m = fmaxf(m, __shfl_xor(m, off));
        float e0 = (v0 > -1e37f) ? __expf(v0 - m) : 0.f;
        float e1 = (v1 > -1e37f) ? __expf(v1 - m) : 0.f;
        float e2 = (v2 > -1e37f) ? __expf(v2 - m) : 0.f;
        float e3 = (v3 > -1e37f) ? __expf(v3 - m) : 0.f;
        p[u][lane] = e0; p[u][lane + 64] = e1; p[u][lane + 128] = e2; p[u][lane + 192] = e3;
        float l = e0 + e1 + e2 + e3;
        #pragma unroll
        for (int off = 32; off; off >>= 1) l += __shfl_xor(l, off);
        if (lane == 0) {
            pm[((size_t)g * NC_ + c) * U_ + u] = m;
            pl[((size_t)g * NC_ + c) * U_ + u] = l;
        }
    }
    __syncthreads();

    // partial PV: wave handles u-quads; lane = (usub, d4)
    const int usub = lane >> 4;
    const int d4 = (lane & 15) * 4;
    for (int qd = wid; qd < (U_ + 3) / 4; qd += 4) {
        int u = qd * 4 + usub;
        int uc = u < U_ ? u : U_ - 1;
        float4 acc = {0.f, 0.f, 0.f, 0.f};
        const short* vbase = vb + ((size_t)g * T_ + j0) * HD_ + d4;
        for (int j = 0; j < JC_; j += 4) {
            float4 pv = *(float4*)&p[uc][j];
            #pragma unroll
            for (int jj = 0; jj < 4; ++jj) {
                float w = (jj == 0) ? pv.x : (jj == 1) ? pv.y : (jj == 2) ? pv.z : pv.w;
                ushort4 vv = *(const ushort4*)(vbase + (j + jj) * HD_);
                acc.x += w * b2f((short)vv.x);
                acc.y += w * b2f((short)vv.y);
                acc.z += w * b2f((short)vv.z);
                acc.w += w * b2f((short)vv.w);
            }
        }
        if (u < U_)
            *(float4*)&po[(((size_t)g * NC_ + c) * U_ + u) * HD_ + d4] = acc;
    }
}

// ---------------------------------------------------------------------------
// Combine chunk partials -> selo[g][u][d]
// ---------------------------------------------------------------------------
__global__ __launch_bounds__(256) void attn_combine(
    const float* __restrict__ pm, const float* __restrict__ pl,
    const float* __restrict__ po, float* __restrict__ selo)
{
    const int g = blockIdx.x;
    const int tid = threadIdx.x;
    const int ug = tid >> 6, d = tid & 63;
    for (int u = ug; u < U_; u += 4) {
        float m = -3e38f;
        float mc[NC_], lc[NC_];
        #pragma unroll
        for (int c = 0; c < NC_; ++c) {
            mc[c] = pm[((size_t)g * NC_ + c) * U_ + u];
            lc[c] = pl[((size_t)g * NC_ + c) * U_ + u];
            m = fmaxf(m, mc[c]);
        }
        float l = 0.f, o = 0.f;
        #pragma unroll
        for (int c = 0; c < NC_; ++c) {
            if (lc[c] > 0.f) {
                float w = __expf(mc[c] - m);
                l += lc[c] * w;
                o += po[(((size_t)g * NC_ + c) * U_ + u) * HD_ + d] * w;
            }
        }
        selo[((size_t)g * U_ + u) * HD_ + d] = o / l;
    }
}

// ---------------------------------------------------------------------------
__global__ __launch_bounds__(256) void fill_kernel(
    const float* __restrict__ bo, float* __restrict__ out)
{
    const size_t i = (size_t)blockIdx.x * 256 + threadIdx.x;   // float4 index
    float4 bv = *(const float4*)(bo + ((i & 255) << 2));
    *(float4*)(out + i * 4) = bv;
}

__global__ __launch_bounds__(256) void oproj_kernel(
    const float* __restrict__ selo, const int* __restrict__ idxb,
    const float* __restrict__ Wo, float* __restrict__ out)
{
    __shared__ float sel[64];
    const int blk = blockIdx.x;
    const int h = (blk / U_) % H_;
    const int b = blk / (U_ * H_);
    const int t = idxb[blk];
    const int tid = threadIdx.x;
    if (tid < 64) sel[tid] = selo[(size_t)blk * HD_ + tid];
    __syncthreads();
    float* orow = out + ((size_t)b * T_ + t) * D_;
    #pragma unroll
    for (int rep = 0; rep < 4; ++rep) {
        int n = tid + rep * 256;
        float c = 0.f;
        #pragma unroll 8
        for (int dd = 0; dd < 64; ++dd)
            c += sel[dd] * Wo[(size_t)(h * HD_ + dd) * D_ + n];
        atomicAdd(orow + n, c);
    }
}

// ---------------------------------------------------------------------------
extern "C" void kernel_launch(void* const* d_in, const int* in_sizes, int n_in,
                              void* d_out, int out_size, void* d_ws, size_t ws_size,
                              hipStream_t stream)
{
    const float* x  = (const float*)d_in[0];
    const float* Wq = (const float*)d_in[1];
    const float* bq = (const float*)d_in[2];
    const float* Wk = (const float*)d_in[3];
    const float* bk = (const float*)d_in[4];
    const float* Wv = (const float*)d_in[5];
    const float* bv = (const float*)d_in[6];
    const float* Wo = (const float*)d_in[7];
    const float* bo = (const float*)d_in[8];
    float* out = (float*)d_out;

    char* ws = (char*)d_ws;
    short* xh    = (short*)(ws);                        // 16,777,216
    short* xl    = (short*)(ws + 16777216);             // 16,777,216
    short* wqh   = (short*)(ws + 33554432);             //  2,097,152
    short* wql   = (short*)(ws + 35651584);             //  2,097,152
    short* wkvt  = (short*)(ws + 37748736);             //  4,194,304
    short* kb    = (short*)(ws + 41943040);             // 16,777,216
    short* vb    = (short*)(ws + 58720256);             // 16,777,216
    float* qnorm = (float*)(ws + 75497472);             //    524,288
    int*   idxb  = (int*)  (ws + 76021760);             //     16,384
    float* selo  = (float*)(ws + 76038144);             //    622,592
    short* qbuf  = (short*)(ws + 76660736);             // 16,777,216 (end 93,437,952)
    // partials overlay xh/xl (free after the GEMMs):
    float* po    = (float*)(ws);                        //  4,980,736
    float* pm    = (float*)(ws + 16777216);             //     77,824
    float* pl    = (float*)(ws + 16777216 + 131072);    //     77,824

    convx_kernel<<<M_ * D_ / 1024, 256, 0, stream>>>(x, xh, xl);
    convw_kernel<<<dim3(32, 32, 3), 256, 0, stream>>>(Wq, Wk, Wv, wqh, wql, wkvt);
    kv_gemm<<<dim3(M_ / 128, 16), 256, 0, stream>>>(xh, wkvt, bk, bv, kb, vb);
    q_gemm<<<dim3(M_ / 128, 8), 256, 0, stream>>>(xh, xl, wqh, wql, bq, qnorm, qbuf);
    topk_kernel<<<B_ * H_, 64, 0, stream>>>(qnorm, idxb);
    attn_part<<<64 * NC_, 256, 0, stream>>>(qbuf, kb, vb, idxb, pm, pl, po);
    attn_combine<<<B_ * H_, 256, 0, stream>>>(pm, pl, po, selo);
    fill_kernel<<<(M_ * D_ / 4) / 256, 256, 0, stream>>>(bo, out);
    oproj_kernel<<<B_ * H_ * U_, 256, 0, stream>>>(selo, idxb, Wo, out);
}